// Round 16
// baseline (350.325 us; speedup 1.0000x reference)
//
#include <hip/hip_runtime.h>
#include <stdint.h>

#define LOG2E 1.44269504088896340f

typedef __attribute__((ext_vector_type(4))) float f32x4;
typedef __attribute__((ext_vector_type(8))) short bf16x8;

// software RNE bf16 — used in PREP kernels only (not perf-critical there)
__device__ __forceinline__ unsigned int f2bf1(float f) {
  unsigned int u = __builtin_bit_cast(unsigned int, f);
  u += 0x7fffu + ((u >> 16) & 1u);   // RNE to bf16
  return u >> 16;
}

// main kernel: hardware packed convert, 1 instr per pair (RNE). R8's spill
// was the hip_bf16 aggregate types, NOT the cvt; raw asm keeps registers.
__device__ __forceinline__ unsigned int f2bf_pk(float lo, float hi) {
  unsigned int r;
  asm("v_cvt_pk_bf16_f32 %0, %1, %2" : "=v"(r) : "v"(lo), "v"(hi));
  return r;
}
__device__ __forceinline__ bf16x8 pack8(f32x4 a, f32x4 b) {
  union { uint4 u; bf16x8 v; } r;
  r.u.x = f2bf_pk(a[0], a[1]);
  r.u.y = f2bf_pk(a[2], a[3]);
  r.u.z = f2bf_pk(b[0], b[1]);
  r.u.w = f2bf_pk(b[2], b[3]);
  return r.v;
}
__device__ __forceinline__ f32x4 vmax4(f32x4 a, f32x4 b) {
  f32x4 r;
  r[0] = fmaxf(a[0], b[0]); r[1] = fmaxf(a[1], b[1]);
  r[2] = fmaxf(a[2], b[2]); r[3] = fmaxf(a[3], b[3]);
  return r;
}

// ---------------- prep kernels (run every call; deterministic) ----------------

// q rows get 1/sqrt(32) * LOG2E so QK^T lands in log2 units (softmax uses
// exp2 with no per-element rescale).
__global__ void prep_wts(const float* __restrict__ qkv_w, const float* __restrict__ proj_w,
                         unsigned short* __restrict__ qkv_wb, unsigned short* __restrict__ proj_wb) {
  int i = blockIdx.x * blockDim.x + threadIdx.x;
  int stride = gridDim.x * blockDim.x;
  for (int idx = i; idx < 768 * 256; idx += stride) {
    float v = qkv_w[idx];
    if (idx < 256 * 256) v *= 0.17677669529663687f * LOG2E;
    qkv_wb[idx] = (unsigned short)f2bf1(v);
  }
  for (int idx = i; idx < 256 * 256; idx += stride)
    proj_wb[idx] = (unsigned short)f2bf1(proj_w[idx]);
}

__global__ void prep_cpb(const float* __restrict__ w1, const float* __restrict__ b1,
                         const float* __restrict__ w2, float* __restrict__ t_buf) {
  int row = blockIdx.x;        // 0..224
  int l = threadIdx.x;         // 0..63
  int a = row / 15, bb = row % 15;
  float va = (a - 7) * (8.0f / 7.0f);
  float vb = (bb - 7) * (8.0f / 7.0f);
  float x0 = (va > 0.f ? 1.f : (va < 0.f ? -1.f : 0.f)) * log2f(fabsf(va) + 1.0f) * (1.0f / 3.0f);
  float x1 = (vb > 0.f ? 1.f : (vb < 0.f ? -1.f : 0.f)) * log2f(fabsf(vb) + 1.0f) * (1.0f / 3.0f);
  float acc[8];
  #pragma unroll
  for (int o = 0; o < 8; o++) acc[o] = 0.f;
  for (int jj = 0; jj < 8; jj++) {
    int j = jj * 64 + l;
    float h = fmaf(x0, w1[2 * j], fmaf(x1, w1[2 * j + 1], b1[j]));
    h = fmaxf(h, 0.f);
    #pragma unroll
    for (int o = 0; o < 8; o++) acc[o] = fmaf(h, w2[o * 512 + j], acc[o]);
  }
  #pragma unroll
  for (int m = 1; m < 64; m <<= 1) {
    #pragma unroll
    for (int o = 0; o < 8; o++) acc[o] += __shfl_xor(acc[o], m, 64);
  }
  if (l < 8) t_buf[row * 8 + l] = acc[l];
}

// bias_sw[h][ti][tj][lane][jj] = 16*sigmoid(t)*LOG2E (log2 units, matches Wq)
__global__ void prep_bias(const float* __restrict__ t_buf, float* __restrict__ bias_sw) {
  int blk = blockIdx.x;   // h*16 + ti*4 + tj
  int l = threadIdx.x;
  int h = blk >> 4, ti = (blk >> 2) & 3, tj = blk & 3;
  int q = tj * 16 + (l & 15);
  int kvb = ti * 16 + (l >> 4) * 4;
  int qi = q >> 3, qj = q & 7;
  #pragma unroll
  for (int jj = 0; jj < 4; jj++) {
    int kv = kvb + jj, ki = kv >> 3, kj = kv & 7;
    int idx = (qi - ki + 7) * 15 + (qj - kj + 7);
    float tv = t_buf[idx * 8 + h];
    float s = 16.0f / (1.0f + exp2f(-tv * LOG2E));
    bias_sw[(blk * 64 + l) * 4 + jj] = s * LOG2E;
  }
}

// ---------------- fused main kernel ----------------
// grid 4096, 512 threads = 8 waves, wave = head. LDS: only xs[64][264] bf16
// (33792 B). SEPARATE V/K/Q passes (merged passes regress — R11; fused accs
// spill — R5). Attention phase: all 16 S-MFMAs bulk-issued (sl[4][4], R2
// precedent fits (512,4)), 16 bias loads pipelined behind them, then 4
// INDEPENDENT softmax+PV chains unrolled for cross-tj ILP (R15 showed the
// serial per-tj chain was the exposed-latency hotspot). Tree reductions.
// Packing via v_cvt_pk_bf16_f32 asm (R15: VALU 29->20%).
__global__ __launch_bounds__(512, 4)
void win_attn(const float* __restrict__ x, const unsigned short* __restrict__ qkv_wb,
              const unsigned short* __restrict__ proj_wb, const float* __restrict__ proj_b,
              const float* __restrict__ bias_sw, float* __restrict__ out) {
  extern __shared__ char smem[];
  const int b = blockIdx.x;
  const int tid = threadIdx.x;
  const int wid = tid >> 6;        // head
  const int lane = tid & 63;
  const int c = lane & 15, g = lane >> 4;
  const f32x4 fzero = {0.f, 0.f, 0.f, 0.f};

  unsigned short* xs = (unsigned short*)smem;   // [64][264] bf16; later holds O

  // ---- stage x -> LDS bf16 ----
  {
    const float* xb = x + (size_t)b * 16384;
    int row = tid >> 3, ch = (tid & 7) * 8;
    #pragma unroll
    for (int qq = 0; qq < 4; qq++) {
      const float4* src = (const float4*)(xb + row * 256 + ch + qq * 64);
      float4 f0 = src[0], f1 = src[1];
      uint4 pk;
      pk.x = f2bf_pk(f0.x, f0.y);
      pk.y = f2bf_pk(f0.z, f0.w);
      pk.z = f2bf_pk(f1.x, f1.y);
      pk.w = f2bf_pk(f1.z, f1.w);
      *(uint4*)(xs + row * 264 + ch + qq * 64) = pk;
    }
  }
  __syncthreads();

  // ---- pass A: V = x @ Wv^T (token-major); V "transpose" is a free pack ----
  bf16x8 vf[2][2];   // [d-tile][token-32-half]
  {
    f32x4 av[4][2];
    #pragma unroll
    for (int t = 0; t < 4; t++) { av[t][0] = fzero; av[t][1] = fzero; }
    const unsigned short* wv0 = qkv_wb + (size_t)(512 + wid * 32 + c) * 256 + g * 8;
    const unsigned short* wv1 = qkv_wb + (size_t)(512 + wid * 32 + 16 + c) * 256 + g * 8;
    #pragma unroll
    for (int kk = 0; kk < 8; kk++) {
      bf16x8 xf[4];
      #pragma unroll
      for (int t = 0; t < 4; t++)
        xf[t] = *(const bf16x8*)(xs + (t * 16 + c) * 264 + kk * 32 + g * 8);
      bf16x8 w0 = *(const bf16x8*)(wv0 + kk * 32);
      bf16x8 w1 = *(const bf16x8*)(wv1 + kk * 32);
      __builtin_amdgcn_s_setprio(1);
      #pragma unroll
      for (int t = 0; t < 4; t++) {
        av[t][0] = __builtin_amdgcn_mfma_f32_16x16x32_bf16(xf[t], w0, av[t][0], 0, 0, 0);
        av[t][1] = __builtin_amdgcn_mfma_f32_16x16x32_bf16(xf[t], w1, av[t][1], 0, 0, 0);
      }
      __builtin_amdgcn_s_setprio(0);
    }
    // av[t][fv] elem jj = V[token=t*16+4g+jj][d=fv*16+c] -> PV A-frag slots
    #pragma unroll
    for (int h = 0; h < 2; h++)
      #pragma unroll
      for (int dt = 0; dt < 2; dt++)
        vf[dt][h] = pack8(av[2 * h][dt], av[2 * h + 1][dt]);
  }

  // ---- pass B-K: K d-major: C[feature][token] = mfma(Wk, x^T) ----
  bf16x8 kf[4];
  {
    f32x4 ak[2][4];
    #pragma unroll
    for (int f = 0; f < 2; f++)
      #pragma unroll
      for (int t = 0; t < 4; t++) ak[f][t] = fzero;
    const unsigned short* wk0 = qkv_wb + (size_t)(256 + wid * 32 + c) * 256 + g * 8;
    const unsigned short* wk1 = qkv_wb + (size_t)(256 + wid * 32 + 16 + c) * 256 + g * 8;
    #pragma unroll
    for (int kk = 0; kk < 8; kk++) {
      bf16x8 xf[4];
      #pragma unroll
      for (int t = 0; t < 4; t++)
        xf[t] = *(const bf16x8*)(xs + (t * 16 + c) * 264 + kk * 32 + g * 8);
      bf16x8 w0 = *(const bf16x8*)(wk0 + kk * 32);
      bf16x8 w1 = *(const bf16x8*)(wk1 + kk * 32);
      __builtin_amdgcn_s_setprio(1);
      #pragma unroll
      for (int t = 0; t < 4; t++) {
        ak[0][t] = __builtin_amdgcn_mfma_f32_16x16x32_bf16(w0, xf[t], ak[0][t], 0, 0, 0);
        ak[1][t] = __builtin_amdgcn_mfma_f32_16x16x32_bf16(w1, xf[t], ak[1][t], 0, 0, 0);
      }
      __builtin_amdgcn_s_setprio(0);
    }
    #pragma unroll
    for (int t = 0; t < 4; t++) kf[t] = pack8(ak[0][t], ak[1][t]);
  }

  // ---- pass B-Q: Q d-major (scale*LOG2E folded into Wq) ----
  bf16x8 qf[4];
  {
    f32x4 aq[2][4];
    #pragma unroll
    for (int f = 0; f < 2; f++)
      #pragma unroll
      for (int t = 0; t < 4; t++) aq[f][t] = fzero;
    const unsigned short* wq0 = qkv_wb + (size_t)(wid * 32 + c) * 256 + g * 8;
    const unsigned short* wq1 = qkv_wb + (size_t)(wid * 32 + 16 + c) * 256 + g * 8;
    #pragma unroll
    for (int kk = 0; kk < 8; kk++) {
      bf16x8 xf[4];
      #pragma unroll
      for (int t = 0; t < 4; t++)
        xf[t] = *(const bf16x8*)(xs + (t * 16 + c) * 264 + kk * 32 + g * 8);
      bf16x8 w0 = *(const bf16x8*)(wq0 + kk * 32);
      bf16x8 w1 = *(const bf16x8*)(wq1 + kk * 32);
      __builtin_amdgcn_s_setprio(1);
      #pragma unroll
      for (int t = 0; t < 4; t++) {
        aq[0][t] = __builtin_amdgcn_mfma_f32_16x16x32_bf16(w0, xf[t], aq[0][t], 0, 0, 0);
        aq[1][t] = __builtin_amdgcn_mfma_f32_16x16x32_bf16(w1, xf[t], aq[1][t], 0, 0, 0);
      }
      __builtin_amdgcn_s_setprio(0);
    }
    #pragma unroll
    for (int t = 0; t < 4; t++) qf[t] = pack8(aq[0][t], aq[1][t]);
  }

  // ---- S^T: all 16 tiles bulk-issued (MFMA pipe streams; bias loads
  //      pipeline behind them) ----
  f32x4 sl[4][4];   // [tj][ti]
  __builtin_amdgcn_s_setprio(1);
  #pragma unroll
  for (int tj = 0; tj < 4; tj++)
    #pragma unroll
    for (int ti = 0; ti < 4; ti++)
      sl[tj][ti] = __builtin_amdgcn_mfma_f32_16x16x32_bf16(kf[ti], qf[tj], fzero, 0, 0, 0);
  __builtin_amdgcn_s_setprio(0);

  #pragma unroll
  for (int tj = 0; tj < 4; tj++)
    #pragma unroll
    for (int ti = 0; ti < 4; ti++)
      sl[tj][ti] += *(const f32x4*)(bias_sw + ((size_t)((wid * 4 + ti) * 4 + tj) * 64 + lane) * 4);

  // ---- softmax + PV: 4 independent chains (cross-tj ILP), tree reduces ----
  f32x4 o[2][4];   // [d-tile][q-tile]
  float rinv[4];
  #pragma unroll
  for (int dt = 0; dt < 2; dt++)
    #pragma unroll
    for (int tq = 0; tq < 4; tq++) o[dt][tq] = fzero;

  #pragma unroll
  for (int tj = 0; tj < 4; tj++) {
    // tree max over 16 in-lane values
    f32x4 m4 = vmax4(vmax4(sl[tj][0], sl[tj][1]), vmax4(sl[tj][2], sl[tj][3]));
    float mx = fmaxf(fmaxf(m4[0], m4[1]), fmaxf(m4[2], m4[3]));
    mx = fmaxf(mx, __shfl_xor(mx, 16, 64));
    mx = fmaxf(mx, __shfl_xor(mx, 32, 64));
    // exp2 (log2 units) + vector tree sum
    f32x4 s4 = fzero;
    #pragma unroll
    for (int ti = 0; ti < 4; ti++) {
      #pragma unroll
      for (int jj = 0; jj < 4; jj++) sl[tj][ti][jj] = exp2f(sl[tj][ti][jj] - mx);
      s4 += sl[tj][ti];
    }
    float sum = (s4[0] + s4[1]) + (s4[2] + s4[3]);
    sum += __shfl_xor(sum, 16, 64);
    sum += __shfl_xor(sum, 32, 64);
    rinv[tj] = 1.0f / sum;
    bf16x8 pb0 = pack8(sl[tj][0], sl[tj][1]);   // unnormalized, in (0,1]
    bf16x8 pb1 = pack8(sl[tj][2], sl[tj][3]);
    __builtin_amdgcn_s_setprio(1);
    #pragma unroll
    for (int dt = 0; dt < 2; dt++) {
      o[dt][tj] = __builtin_amdgcn_mfma_f32_16x16x32_bf16(vf[dt][0], pb0, o[dt][tj], 0, 0, 0);
      o[dt][tj] = __builtin_amdgcn_mfma_f32_16x16x32_bf16(vf[dt][1], pb1, o[dt][tj], 0, 0, 0);
    }
    __builtin_amdgcn_s_setprio(0);
  }

  __syncthreads();   // all waves done reading xs
  // ---- O -> xs (normalize by rinv here): lane holds O[tq*16+c][dt*16+4g+jj] ----
  #pragma unroll
  for (int tq = 0; tq < 4; tq++)
    #pragma unroll
    for (int dt = 0; dt < 2; dt++) {
      uint2 pk;
      pk.x = f2bf_pk(o[dt][tq][0] * rinv[tq], o[dt][tq][1] * rinv[tq]);
      pk.y = f2bf_pk(o[dt][tq][2] * rinv[tq], o[dt][tq][3] * rinv[tq]);
      *(uint2*)(xs + (tq * 16 + c) * 264 + wid * 32 + dt * 16 + g * 4) = pk;
    }
  __syncthreads();

  // ---- out projection (token-major) ----
  f32x4 po[4][2];
  #pragma unroll
  for (int m = 0; m < 4; m++) { po[m][0] = fzero; po[m][1] = fzero; }
  const unsigned short* pw0 = proj_wb + (size_t)(wid * 32 + c) * 256 + g * 8;
  const unsigned short* pw1 = proj_wb + (size_t)(wid * 32 + 16 + c) * 256 + g * 8;
  #pragma unroll
  for (int kk = 0; kk < 8; kk++) {
    bf16x8 a[4];
    #pragma unroll
    for (int m = 0; m < 4; m++)
      a[m] = *(const bf16x8*)(xs + (m * 16 + c) * 264 + kk * 32 + g * 8);
    bf16x8 b0 = *(const bf16x8*)(pw0 + kk * 32);
    bf16x8 b1 = *(const bf16x8*)(pw1 + kk * 32);
    __builtin_amdgcn_s_setprio(1);
    #pragma unroll
    for (int m = 0; m < 4; m++) {
      po[m][0] = __builtin_amdgcn_mfma_f32_16x16x32_bf16(a[m], b0, po[m][0], 0, 0, 0);
      po[m][1] = __builtin_amdgcn_mfma_f32_16x16x32_bf16(a[m], b1, po[m][1], 0, 0, 0);
    }
    __builtin_amdgcn_s_setprio(0);
  }
  float pb0s = proj_b[wid * 32 + c], pb1s = proj_b[wid * 32 + 16 + c];
  float* ob = out + (size_t)b * 16384;
  #pragma unroll
  for (int m = 0; m < 4; m++)
    #pragma unroll
    for (int jj = 0; jj < 4; jj++) {
      int tok = m * 16 + g * 4 + jj;
      ob[tok * 256 + wid * 32 + c]      = po[m][0][jj] + pb0s;
      ob[tok * 256 + wid * 32 + 16 + c] = po[m][1][jj] + pb1s;
    }
}

extern "C" void kernel_launch(void* const* d_in, const int* in_sizes, int n_in,
                              void* d_out, int out_size, void* d_ws, size_t ws_size,
                              hipStream_t stream) {
  const float* x      = (const float*)d_in[0];
  const float* qkv_w  = (const float*)d_in[1];
  const float* proj_w = (const float*)d_in[2];
  const float* proj_b = (const float*)d_in[3];
  const float* cpb_w1 = (const float*)d_in[4];
  const float* cpb_b1 = (const float*)d_in[5];
  const float* cpb_w2 = (const float*)d_in[6];
  float* out = (float*)d_out;

  char* ws = (char*)d_ws;
  unsigned short* qkv_wb = (unsigned short*)(ws);            // 393216 B
  unsigned short* proj_wb = (unsigned short*)(ws + 393216);  // 131072 B
  float* t_buf   = (float*)(ws + 524288);                    // 7200 B
  float* bias_sw = (float*)(ws + 532480);                    // 131072 B

  prep_wts<<<dim3(256), dim3(256), 0, stream>>>(qkv_w, proj_w, qkv_wb, proj_wb);
  prep_cpb<<<dim3(225), dim3(64), 0, stream>>>(cpb_w1, cpb_b1, cpb_w2, t_buf);
  prep_bias<<<dim3(128), dim3(64), 0, stream>>>(t_buf, bias_sw);
  win_attn<<<dim3(4096), dim3(512), 33792, stream>>>(x, qkv_wb, proj_wb, proj_b, bias_sw, out);
}

// Round 17
// 321.904 us; speedup vs baseline: 1.0883x; 1.0883x over previous
//
#include <hip/hip_runtime.h>
#include <stdint.h>

#define LOG2E 1.44269504088896340f

typedef __attribute__((ext_vector_type(4))) float f32x4;
typedef __attribute__((ext_vector_type(8))) short bf16x8;

// software RNE bf16 — used in PREP kernels only (not perf-critical there)
__device__ __forceinline__ unsigned int f2bf1(float f) {
  unsigned int u = __builtin_bit_cast(unsigned int, f);
  u += 0x7fffu + ((u >> 16) & 1u);   // RNE to bf16
  return u >> 16;
}

// main kernel: hardware packed convert, 1 instr per pair (RNE). R8's spill
// was the hip_bf16 aggregate types, NOT the cvt; raw asm keeps registers.
__device__ __forceinline__ unsigned int f2bf_pk(float lo, float hi) {
  unsigned int r;
  asm("v_cvt_pk_bf16_f32 %0, %1, %2" : "=v"(r) : "v"(lo), "v"(hi));
  return r;
}
__device__ __forceinline__ bf16x8 pack8(f32x4 a, f32x4 b) {
  union { uint4 u; bf16x8 v; } r;
  r.u.x = f2bf_pk(a[0], a[1]);
  r.u.y = f2bf_pk(a[2], a[3]);
  r.u.z = f2bf_pk(b[0], b[1]);
  r.u.w = f2bf_pk(b[2], b[3]);
  return r.v;
}

// ---------------- prep kernels (run every call; deterministic) ----------------

// q rows get 1/sqrt(32) * LOG2E so QK^T lands in log2 units (softmax uses
// exp2 with no per-element rescale).
__global__ void prep_wts(const float* __restrict__ qkv_w, const float* __restrict__ proj_w,
                         unsigned short* __restrict__ qkv_wb, unsigned short* __restrict__ proj_wb) {
  int i = blockIdx.x * blockDim.x + threadIdx.x;
  int stride = gridDim.x * blockDim.x;
  for (int idx = i; idx < 768 * 256; idx += stride) {
    float v = qkv_w[idx];
    if (idx < 256 * 256) v *= 0.17677669529663687f * LOG2E;
    qkv_wb[idx] = (unsigned short)f2bf1(v);
  }
  for (int idx = i; idx < 256 * 256; idx += stride)
    proj_wb[idx] = (unsigned short)f2bf1(proj_w[idx]);
}

__global__ void prep_cpb(const float* __restrict__ w1, const float* __restrict__ b1,
                         const float* __restrict__ w2, float* __restrict__ t_buf) {
  int row = blockIdx.x;        // 0..224
  int l = threadIdx.x;         // 0..63
  int a = row / 15, bb = row % 15;
  float va = (a - 7) * (8.0f / 7.0f);
  float vb = (bb - 7) * (8.0f / 7.0f);
  float x0 = (va > 0.f ? 1.f : (va < 0.f ? -1.f : 0.f)) * log2f(fabsf(va) + 1.0f) * (1.0f / 3.0f);
  float x1 = (vb > 0.f ? 1.f : (vb < 0.f ? -1.f : 0.f)) * log2f(fabsf(vb) + 1.0f) * (1.0f / 3.0f);
  float acc[8];
  #pragma unroll
  for (int o = 0; o < 8; o++) acc[o] = 0.f;
  for (int jj = 0; jj < 8; jj++) {
    int j = jj * 64 + l;
    float h = fmaf(x0, w1[2 * j], fmaf(x1, w1[2 * j + 1], b1[j]));
    h = fmaxf(h, 0.f);
    #pragma unroll
    for (int o = 0; o < 8; o++) acc[o] = fmaf(h, w2[o * 512 + j], acc[o]);
  }
  #pragma unroll
  for (int m = 1; m < 64; m <<= 1) {
    #pragma unroll
    for (int o = 0; o < 8; o++) acc[o] += __shfl_xor(acc[o], m, 64);
  }
  if (l < 8) t_buf[row * 8 + l] = acc[l];
}

// bias_sw[h][ti][tj][lane][jj] = 16*sigmoid(t)*LOG2E (log2 units, matches Wq)
__global__ void prep_bias(const float* __restrict__ t_buf, float* __restrict__ bias_sw) {
  int blk = blockIdx.x;   // h*16 + ti*4 + tj
  int l = threadIdx.x;
  int h = blk >> 4, ti = (blk >> 2) & 3, tj = blk & 3;
  int q = tj * 16 + (l & 15);
  int kvb = ti * 16 + (l >> 4) * 4;
  int qi = q >> 3, qj = q & 7;
  #pragma unroll
  for (int jj = 0; jj < 4; jj++) {
    int kv = kvb + jj, ki = kv >> 3, kj = kv & 7;
    int idx = (qi - ki + 7) * 15 + (qj - kj + 7);
    float tv = t_buf[idx * 8 + h];
    float s = 16.0f / (1.0f + exp2f(-tv * LOG2E));
    bias_sw[(blk * 64 + l) * 4 + jj] = s * LOG2E;
  }
}

// ---------------- fused main kernel ----------------
// grid 4096, 512 threads = 8 waves, wave = head. LDS: only xs[64][264] bf16
// (33792 B). SEPARATE V/K/Q passes — R9/R12/R15-proven (merged passes
// regress: R11; fused accs spill: R5; bulk S^T serializes: R16). Softmax in
// log2 units; P unnormalized, rinv at O-epilogue; cvt_pk asm packing.
// NEW vs R15: 1-deep bias prefetch — bias[tj+1] issues right after bias[tj]
// is consumed, hiding its ~200cyc L2 latency under softmax+PV of tile tj.
__global__ __launch_bounds__(512, 4)
void win_attn(const float* __restrict__ x, const unsigned short* __restrict__ qkv_wb,
              const unsigned short* __restrict__ proj_wb, const float* __restrict__ proj_b,
              const float* __restrict__ bias_sw, float* __restrict__ out) {
  extern __shared__ char smem[];
  const int b = blockIdx.x;
  const int tid = threadIdx.x;
  const int wid = tid >> 6;        // head
  const int lane = tid & 63;
  const int c = lane & 15, g = lane >> 4;
  const f32x4 fzero = {0.f, 0.f, 0.f, 0.f};

  unsigned short* xs = (unsigned short*)smem;   // [64][264] bf16; later holds O

  // ---- stage x -> LDS bf16 ----
  {
    const float* xb = x + (size_t)b * 16384;
    int row = tid >> 3, ch = (tid & 7) * 8;
    #pragma unroll
    for (int qq = 0; qq < 4; qq++) {
      const float4* src = (const float4*)(xb + row * 256 + ch + qq * 64);
      float4 f0 = src[0], f1 = src[1];
      uint4 pk;
      pk.x = f2bf_pk(f0.x, f0.y);
      pk.y = f2bf_pk(f0.z, f0.w);
      pk.z = f2bf_pk(f1.x, f1.y);
      pk.w = f2bf_pk(f1.z, f1.w);
      *(uint4*)(xs + row * 264 + ch + qq * 64) = pk;
    }
  }
  __syncthreads();

  // ---- pass A: V = x @ Wv^T (token-major); V "transpose" is a free pack ----
  bf16x8 vf[2][2];   // [d-tile][token-32-half]
  {
    f32x4 av[4][2];
    #pragma unroll
    for (int t = 0; t < 4; t++) { av[t][0] = fzero; av[t][1] = fzero; }
    const unsigned short* wv0 = qkv_wb + (size_t)(512 + wid * 32 + c) * 256 + g * 8;
    const unsigned short* wv1 = qkv_wb + (size_t)(512 + wid * 32 + 16 + c) * 256 + g * 8;
    #pragma unroll
    for (int kk = 0; kk < 8; kk++) {
      bf16x8 xf[4];
      #pragma unroll
      for (int t = 0; t < 4; t++)
        xf[t] = *(const bf16x8*)(xs + (t * 16 + c) * 264 + kk * 32 + g * 8);
      bf16x8 w0 = *(const bf16x8*)(wv0 + kk * 32);
      bf16x8 w1 = *(const bf16x8*)(wv1 + kk * 32);
      __builtin_amdgcn_s_setprio(1);
      #pragma unroll
      for (int t = 0; t < 4; t++) {
        av[t][0] = __builtin_amdgcn_mfma_f32_16x16x32_bf16(xf[t], w0, av[t][0], 0, 0, 0);
        av[t][1] = __builtin_amdgcn_mfma_f32_16x16x32_bf16(xf[t], w1, av[t][1], 0, 0, 0);
      }
      __builtin_amdgcn_s_setprio(0);
    }
    // av[t][fv] elem jj = V[token=t*16+4g+jj][d=fv*16+c] -> PV A-frag slots
    #pragma unroll
    for (int h = 0; h < 2; h++)
      #pragma unroll
      for (int dt = 0; dt < 2; dt++)
        vf[dt][h] = pack8(av[2 * h][dt], av[2 * h + 1][dt]);
  }

  // ---- pass B-K: K d-major: C[feature][token] = mfma(Wk, x^T) ----
  bf16x8 kf[4];
  {
    f32x4 ak[2][4];
    #pragma unroll
    for (int f = 0; f < 2; f++)
      #pragma unroll
      for (int t = 0; t < 4; t++) ak[f][t] = fzero;
    const unsigned short* wk0 = qkv_wb + (size_t)(256 + wid * 32 + c) * 256 + g * 8;
    const unsigned short* wk1 = qkv_wb + (size_t)(256 + wid * 32 + 16 + c) * 256 + g * 8;
    #pragma unroll
    for (int kk = 0; kk < 8; kk++) {
      bf16x8 xf[4];
      #pragma unroll
      for (int t = 0; t < 4; t++)
        xf[t] = *(const bf16x8*)(xs + (t * 16 + c) * 264 + kk * 32 + g * 8);
      bf16x8 w0 = *(const bf16x8*)(wk0 + kk * 32);
      bf16x8 w1 = *(const bf16x8*)(wk1 + kk * 32);
      __builtin_amdgcn_s_setprio(1);
      #pragma unroll
      for (int t = 0; t < 4; t++) {
        ak[0][t] = __builtin_amdgcn_mfma_f32_16x16x32_bf16(w0, xf[t], ak[0][t], 0, 0, 0);
        ak[1][t] = __builtin_amdgcn_mfma_f32_16x16x32_bf16(w1, xf[t], ak[1][t], 0, 0, 0);
      }
      __builtin_amdgcn_s_setprio(0);
    }
    #pragma unroll
    for (int t = 0; t < 4; t++) kf[t] = pack8(ak[0][t], ak[1][t]);
  }

  // ---- pass B-Q: Q d-major (scale*LOG2E folded into Wq) ----
  bf16x8 qf[4];
  {
    f32x4 aq[2][4];
    #pragma unroll
    for (int f = 0; f < 2; f++)
      #pragma unroll
      for (int t = 0; t < 4; t++) aq[f][t] = fzero;
    const unsigned short* wq0 = qkv_wb + (size_t)(wid * 32 + c) * 256 + g * 8;
    const unsigned short* wq1 = qkv_wb + (size_t)(wid * 32 + 16 + c) * 256 + g * 8;
    #pragma unroll
    for (int kk = 0; kk < 8; kk++) {
      bf16x8 xf[4];
      #pragma unroll
      for (int t = 0; t < 4; t++)
        xf[t] = *(const bf16x8*)(xs + (t * 16 + c) * 264 + kk * 32 + g * 8);
      bf16x8 w0 = *(const bf16x8*)(wq0 + kk * 32);
      bf16x8 w1 = *(const bf16x8*)(wq1 + kk * 32);
      __builtin_amdgcn_s_setprio(1);
      #pragma unroll
      for (int t = 0; t < 4; t++) {
        aq[0][t] = __builtin_amdgcn_mfma_f32_16x16x32_bf16(w0, xf[t], aq[0][t], 0, 0, 0);
        aq[1][t] = __builtin_amdgcn_mfma_f32_16x16x32_bf16(w1, xf[t], aq[1][t], 0, 0, 0);
      }
      __builtin_amdgcn_s_setprio(0);
    }
    #pragma unroll
    for (int t = 0; t < 4; t++) qf[t] = pack8(aq[0][t], aq[1][t]);
  }

  // ---- fused S^T + bias(1-deep prefetch) + softmax(log2) + PV ----
  f32x4 o[2][4];   // [d-tile][q-tile]
  float rinv[4];
  #pragma unroll
  for (int dt = 0; dt < 2; dt++)
    #pragma unroll
    for (int tq = 0; tq < 4; tq++) o[dt][tq] = fzero;

  const float* bias_base = bias_sw + (size_t)wid * 16 * 64 * 4 + (size_t)lane * 4;
  f32x4 bias_pf[4];
  #pragma unroll
  for (int ti = 0; ti < 4; ti++)   // prologue: bias for tj=0
    bias_pf[ti] = *(const f32x4*)(bias_base + (size_t)(ti * 4 + 0) * 64 * 4);

  #pragma unroll
  for (int tj = 0; tj < 4; tj++) {
    f32x4 sl[4];
    __builtin_amdgcn_s_setprio(1);
    #pragma unroll
    for (int ti = 0; ti < 4; ti++)
      sl[ti] = __builtin_amdgcn_mfma_f32_16x16x32_bf16(kf[ti], qf[tj], fzero, 0, 0, 0);
    __builtin_amdgcn_s_setprio(0);
    #pragma unroll
    for (int ti = 0; ti < 4; ti++)
      sl[ti] += bias_pf[ti];
    if (tj < 3) {
      #pragma unroll
      for (int ti = 0; ti < 4; ti++)   // issue next tile's bias; latency hides
        bias_pf[ti] = *(const f32x4*)(bias_base + (size_t)(ti * 4 + tj + 1) * 64 * 4);
    }

    float mx = -1e30f;
    #pragma unroll
    for (int ti = 0; ti < 4; ti++)
      #pragma unroll
      for (int jj = 0; jj < 4; jj++) mx = fmaxf(mx, sl[ti][jj]);
    mx = fmaxf(mx, __shfl_xor(mx, 16, 64));
    mx = fmaxf(mx, __shfl_xor(mx, 32, 64));
    float sum = 0.f;
    #pragma unroll
    for (int ti = 0; ti < 4; ti++)
      #pragma unroll
      for (int jj = 0; jj < 4; jj++) {
        float e = exp2f(sl[ti][jj] - mx);   // already log2 units
        sl[ti][jj] = e;
        sum += e;
      }
    sum += __shfl_xor(sum, 16, 64);
    sum += __shfl_xor(sum, 32, 64);
    rinv[tj] = 1.0f / sum;
    bf16x8 pb0 = pack8(sl[0], sl[1]);   // unnormalized, values in (0,1]
    bf16x8 pb1 = pack8(sl[2], sl[3]);
    __builtin_amdgcn_s_setprio(1);
    #pragma unroll
    for (int dt = 0; dt < 2; dt++) {
      o[dt][tj] = __builtin_amdgcn_mfma_f32_16x16x32_bf16(vf[dt][0], pb0, o[dt][tj], 0, 0, 0);
      o[dt][tj] = __builtin_amdgcn_mfma_f32_16x16x32_bf16(vf[dt][1], pb1, o[dt][tj], 0, 0, 0);
    }
    __builtin_amdgcn_s_setprio(0);
  }

  __syncthreads();   // all waves done reading xs
  // ---- O -> xs (normalize by rinv here): lane holds O[tq*16+c][dt*16+4g+jj] ----
  #pragma unroll
  for (int tq = 0; tq < 4; tq++)
    #pragma unroll
    for (int dt = 0; dt < 2; dt++) {
      uint2 pk;
      pk.x = f2bf_pk(o[dt][tq][0] * rinv[tq], o[dt][tq][1] * rinv[tq]);
      pk.y = f2bf_pk(o[dt][tq][2] * rinv[tq], o[dt][tq][3] * rinv[tq]);
      *(uint2*)(xs + (tq * 16 + c) * 264 + wid * 32 + dt * 16 + g * 4) = pk;
    }
  __syncthreads();

  // ---- out projection (token-major) ----
  f32x4 po[4][2];
  #pragma unroll
  for (int m = 0; m < 4; m++) { po[m][0] = fzero; po[m][1] = fzero; }
  const unsigned short* pw0 = proj_wb + (size_t)(wid * 32 + c) * 256 + g * 8;
  const unsigned short* pw1 = proj_wb + (size_t)(wid * 32 + 16 + c) * 256 + g * 8;
  #pragma unroll
  for (int kk = 0; kk < 8; kk++) {
    bf16x8 a[4];
    #pragma unroll
    for (int m = 0; m < 4; m++)
      a[m] = *(const bf16x8*)(xs + (m * 16 + c) * 264 + kk * 32 + g * 8);
    bf16x8 b0 = *(const bf16x8*)(pw0 + kk * 32);
    bf16x8 b1 = *(const bf16x8*)(pw1 + kk * 32);
    __builtin_amdgcn_s_setprio(1);
    #pragma unroll
    for (int m = 0; m < 4; m++) {
      po[m][0] = __builtin_amdgcn_mfma_f32_16x16x32_bf16(a[m], b0, po[m][0], 0, 0, 0);
      po[m][1] = __builtin_amdgcn_mfma_f32_16x16x32_bf16(a[m], b1, po[m][1], 0, 0, 0);
    }
    __builtin_amdgcn_s_setprio(0);
  }
  float pb0s = proj_b[wid * 32 + c], pb1s = proj_b[wid * 32 + 16 + c];
  float* ob = out + (size_t)b * 16384;
  #pragma unroll
  for (int m = 0; m < 4; m++)
    #pragma unroll
    for (int jj = 0; jj < 4; jj++) {
      int tok = m * 16 + g * 4 + jj;
      ob[tok * 256 + wid * 32 + c]      = po[m][0][jj] + pb0s;
      ob[tok * 256 + wid * 32 + 16 + c] = po[m][1][jj] + pb1s;
    }
}

extern "C" void kernel_launch(void* const* d_in, const int* in_sizes, int n_in,
                              void* d_out, int out_size, void* d_ws, size_t ws_size,
                              hipStream_t stream) {
  const float* x      = (const float*)d_in[0];
  const float* qkv_w  = (const float*)d_in[1];
  const float* proj_w = (const float*)d_in[2];
  const float* proj_b = (const float*)d_in[3];
  const float* cpb_w1 = (const float*)d_in[4];
  const float* cpb_b1 = (const float*)d_in[5];
  const float* cpb_w2 = (const float*)d_in[6];
  float* out = (float*)d_out;

  char* ws = (char*)d_ws;
  unsigned short* qkv_wb = (unsigned short*)(ws);            // 393216 B
  unsigned short* proj_wb = (unsigned short*)(ws + 393216);  // 131072 B
  float* t_buf   = (float*)(ws + 524288);                    // 7200 B
  float* bias_sw = (float*)(ws + 532480);                    // 131072 B

  prep_wts<<<dim3(256), dim3(256), 0, stream>>>(qkv_w, proj_w, qkv_wb, proj_wb);
  prep_cpb<<<dim3(225), dim3(64), 0, stream>>>(cpb_w1, cpb_b1, cpb_w2, t_buf);
  prep_bias<<<dim3(128), dim3(64), 0, stream>>>(t_buf, bias_sw);
  win_attn<<<dim3(4096), dim3(512), 33792, stream>>>(x, qkv_wb, proj_wb, proj_b, bias_sw, out);
}